// Round 1
// baseline (320.922 us; speedup 1.0000x reference)
//
#include <hip/hip_runtime.h>
#include <math.h>

// QNN: 18-wire state-vector simulation, but only 16 distinct initial states
// (4 data bits). Simulate all 16 columns of U, then probs @ W^T + b, sigmoid,
// and per-batch lookup.
//
// Bit convention: wire w <-> bit position p = 17-w (wire 0 = MSB).
// CNOT cascade per layer == linear permutation P over index bits:
//   P(i): out bit p (p<=16) = parity(i>>p); out bit 17 = parity(i & 0x1FFFF).

#define DIM (1 << 18)
#define NW 18
#define NL 4
#define MM_CH 128
#define MM_CHUNKS (DIM / MM_CH)   // 2048

__device__ __forceinline__ unsigned perm18(unsigned i) {
    unsigned s = i;
    s ^= s >> 1; s ^= s >> 2; s ^= s >> 4; s ^= s >> 8; s ^= s >> 16;
    // s_p = parity(i >> p)
    unsigned out = s & 0x1FFFFu;
    out |= ((s ^ (i >> 17)) & 1u) << 17;   // bit17 = parity(bits 0..16)
    return out;
}

// ---- gate table: cs[l*18+w] = (cos(th/2), sin(th/2)) -----------------------
__global__ void k_setup(const float* qw, float2* cs) {
    int t = threadIdx.x;
    if (t < NL * NW) {
        float th = qw[t] * 0.5f;
        cs[t] = make_float2(cosf(th), sinf(th));
    }
}

// ---- layer 0: product state written with P folded in -----------------------
// amp_j(i) = m * (-i)^k ; m = prod over bits of (c or s); k = #s-factors.
__global__ __launch_bounds__(256) void k_init(const float2* cs, float2* buf0) {
    unsigned i = blockIdx.x * 256u + threadIdx.x;
    float c[NW], s[NW];
#pragma unroll
    for (int w = 0; w < NW; ++w) { float2 v = cs[w]; c[w] = v.x; s[w] = v.y; }
    // address bits p=4..17 (wires 13..0), all start |0>
    float mA = 1.0f;
#pragma unroll
    for (int p = 4; p < 18; ++p) {
        int w = 17 - p;
        mA *= ((i >> p) & 1u) ? s[w] : c[w];
    }
    int kA = __popc(i >> 4);
    unsigned Pi = perm18(i);
    unsigned il = i & 15u;
#pragma unroll
    for (int j = 0; j < 16; ++j) {
        unsigned x = il ^ (unsigned)j;     // mismatch pattern on data bits
        float m = mA;
#pragma unroll
        for (int p = 0; p < 4; ++p) {
            int w = 17 - p;
            m *= ((x >> p) & 1u) ? s[w] : c[w];
        }
        int k = (kA + __popc(x)) & 3;
        float2 a;
        if      (k == 0) a = make_float2( m, 0.f);
        else if (k == 1) a = make_float2(0.f, -m);
        else if (k == 2) a = make_float2(-m, 0.f);
        else             a = make_float2(0.f,  m);
        buf0[(size_t)j * DIM + Pi] = a;
    }
}

// ---- pass A: 13 RX gates on bits 0..12 (wires 5..17), in-place -------------
__global__ __launch_bounds__(256) void k_passA(float2* buf, const float2* cs, int layer) {
    __shared__ float2 t[8192];
    int bx = blockIdx.x;              // 512 = 16 j * 32 blocks
    int j = bx >> 5, blk = bx & 31;
    size_t base = (size_t)j * DIM + (size_t)blk * 8192;
    for (int k = threadIdx.x; k < 8192; k += 256) t[k] = buf[base + k];
    __syncthreads();
    for (int p = 0; p <= 12; ++p) {
        float2 g = cs[layer * NW + (17 - p)];
        float c = g.x, s = g.y;
        int mlow = (1 << p) - 1;
        for (int k = threadIdx.x; k < 4096; k += 256) {
            int i0 = ((k >> p) << (p + 1)) | (k & mlow);
            int i1 = i0 | (1 << p);
            float2 a0 = t[i0], a1 = t[i1];
            t[i0] = make_float2(c * a0.x + s * a1.y, c * a0.y - s * a1.x);
            t[i1] = make_float2(c * a1.x + s * a0.y, c * a1.y - s * a0.x);
        }
        __syncthreads();
    }
    for (int k = threadIdx.x; k < 8192; k += 256) buf[base + k] = t[k];
}

// ---- pass B: 5 RX gates on bits 13..17 (wires 0..4) + P scatter ------------
// If probs != nullptr: emit |amp|^2 instead of the state (final layer).
__global__ __launch_bounds__(256) void k_passB(const float2* in, float2* out,
                                               float* probs, const float2* cs, int layer) {
    __shared__ float2 t[32 * 256];
    int bx = blockIdx.x;              // 512 = 16 j * 32 m
    int j = bx >> 5, m = bx & 31;
    const float2* src = in + (size_t)j * DIM;
    for (int k = threadIdx.x; k < 8192; k += 256) {
        int h = k >> 8, low = k & 255;
        t[k] = src[((size_t)h << 13) | (m << 8) | low];
    }
    __syncthreads();
    for (int q = 0; q <= 4; ++q) {
        float2 g = cs[layer * NW + (4 - q)];   // bit 13+q -> wire 4-q
        float c = g.x, s = g.y;
        int mq = (1 << q) - 1;
        for (int k = threadIdx.x; k < 4096; k += 256) {
            int hh = k >> 8, low = k & 255;
            int h0 = ((hh >> q) << (q + 1)) | (hh & mq);
            int h1 = h0 | (1 << q);
            int i0 = h0 * 256 + low, i1 = h1 * 256 + low;
            float2 a0 = t[i0], a1 = t[i1];
            t[i0] = make_float2(c * a0.x + s * a1.y, c * a0.y - s * a1.x);
            t[i1] = make_float2(c * a1.x + s * a0.y, c * a1.y - s * a0.x);
        }
        __syncthreads();
    }
    if (probs) {
        for (int k = threadIdx.x; k < 8192; k += 256) {
            int h = k >> 8, low = k & 255;
            unsigned i = ((unsigned)h << 13) | (m << 8) | low;
            float2 a = t[k];
            probs[(size_t)j * DIM + perm18(i)] = a.x * a.x + a.y * a.y;
        }
    } else {
        for (int k = threadIdx.x; k < 8192; k += 256) {
            int h = k >> 8, low = k & 255;
            unsigned i = ((unsigned)h << 13) | (m << 8) | low;
            out[(size_t)j * DIM + perm18(i)] = t[k];
        }
    }
}

// ---- probs(16 x DIM) @ W^T(DIM x 64): per-chunk partials -------------------
__global__ __launch_bounds__(256) void k_mm(const float* probs, const float* W, float* partial) {
    __shared__ float Pl[16][MM_CH + 1];
    __shared__ float Wl[64][MM_CH + 1];
    int chunk = blockIdx.x;
    size_t d0 = (size_t)chunk * MM_CH;
    for (int k = threadIdx.x; k < 16 * MM_CH; k += 256) {
        int j = k / MM_CH, d = k % MM_CH;
        Pl[j][d] = probs[(size_t)j * DIM + d0 + d];
    }
    for (int k = threadIdx.x; k < 64 * MM_CH; k += 256) {
        int o = k / MM_CH, d = k % MM_CH;
        Wl[o][d] = W[(size_t)o * DIM + d0 + d];
    }
    __syncthreads();
    int j = threadIdx.x >> 4, og = threadIdx.x & 15;
    float a0 = 0.f, a1 = 0.f, a2 = 0.f, a3 = 0.f;
    for (int d = 0; d < MM_CH; ++d) {
        float p = Pl[j][d];
        a0 += p * Wl[og][d];
        a1 += p * Wl[og + 16][d];
        a2 += p * Wl[og + 32][d];
        a3 += p * Wl[og + 48][d];
    }
    float* dst = partial + (size_t)chunk * 1024 + j * 64;
    dst[og] = a0; dst[og + 16] = a1; dst[og + 32] = a2; dst[og + 48] = a3;
}

// ---- reduce partials -> logits[16][64] (+bias) -----------------------------
__global__ __launch_bounds__(256) void k_reduce(const float* partial, const float* bias, float* logits) {
    int jo = blockIdx.x * 256 + threadIdx.x;   // grid 4 -> 1024
    float sum = 0.f;
    for (int c = 0; c < MM_CHUNKS; ++c) sum += partial[(size_t)c * 1024 + jo];
    logits[jo] = sum + bias[jo & 63];
}

// ---- final: per-batch lookup + sigmoid -------------------------------------
__global__ void k_out(const int* x, const float* logits, float* out) {
    int t = blockIdx.x * 256 + threadIdx.x;    // grid 8 -> 2048
    int b = t >> 6, o = t & 63;
    const int* xb = x + (size_t)b * (16384 * 4);
    int idx = 8 * xb[0] + 4 * xb[1] + 2 * xb[2] + xb[3];
    float z = logits[idx * 64 + o];
    out[t] = 1.f / (1.f + expf(-z));
}

extern "C" void kernel_launch(void* const* d_in, const int* in_sizes, int n_in,
                              void* d_out, int out_size, void* d_ws, size_t ws_size,
                              hipStream_t stream) {
    const int*   x    = (const int*)d_in[0];
    const float* qw   = (const float*)d_in[1];
    const float* W    = (const float*)d_in[2];
    const float* bias = (const float*)d_in[3];
    float* out = (float*)d_out;

    char* ws = (char*)d_ws;
    // layout: [0,576) cs | [4K,8K) logits | [1M, 1M+32M) buf0 | [1M+32M, 1M+64M) buf1
    // probs aliases buf1 (16MB), partial aliases buf0 (8MB) -- both safe by ordering.
    float2* cs      = (float2*)ws;
    float*  logits  = (float*)(ws + 4096);
    float2* buf0    = (float2*)(ws + (1 << 20));
    float2* buf1    = (float2*)(ws + (1 << 20) + (size_t)DIM * 16 * sizeof(float2));
    float*  probs   = (float*)buf1;
    float*  partial = (float*)buf0;

    k_setup<<<1, 128, 0, stream>>>(qw, cs);
    k_init<<<DIM / 256, 256, 0, stream>>>(cs, buf0);

    // layers 1..3 (layer 0 done analytically by k_init)
    // l=1: A in-place buf0, B buf0->buf1
    // l=2: A in-place buf1, B buf1->buf0
    // l=3: A in-place buf0, B buf0->probs (|.|^2)
    k_passA<<<512, 256, 0, stream>>>(buf0, cs, 1);
    k_passB<<<512, 256, 0, stream>>>(buf0, buf1, nullptr, cs, 1);
    k_passA<<<512, 256, 0, stream>>>(buf1, cs, 2);
    k_passB<<<512, 256, 0, stream>>>(buf1, buf0, nullptr, cs, 2);
    k_passA<<<512, 256, 0, stream>>>(buf0, cs, 3);
    k_passB<<<512, 256, 0, stream>>>(buf0, nullptr, probs, cs, 3);

    k_mm<<<MM_CHUNKS, 256, 0, stream>>>(probs, W, partial);
    k_reduce<<<4, 256, 0, stream>>>(partial, bias, logits);
    k_out<<<8, 256, 0, stream>>>(x, logits, out);
}

// Round 2
// 240.699 us; speedup vs baseline: 1.3333x; 1.3333x over previous
//
#include <hip/hip_runtime.h>
#include <math.h>

// QNN: 18-wire state-vector simulation, but only 16 distinct initial states
// (4 data bits). Simulate all 16 columns of U, then probs @ W^T + b, sigmoid,
// and per-batch lookup.
//
// Bit convention: wire w <-> bit position p = 17-w (wire 0 = MSB).
// CNOT cascade per layer == linear permutation P over index bits:
//   P(i): out bit p (p<=16) = parity(i>>p); out bit 17 = parity(i & 0x1FFFF).

#define DIM (1 << 18)
#define NW 18
#define NL 4
#define MM_CH 128
#define MM_CPB 4                        // chunks accumulated per block in k_mm
#define MM_CHUNKS (DIM / MM_CH)         // 2048
#define MM_BLOCKS (MM_CHUNKS / MM_CPB)  // 512 partial rows

__device__ __forceinline__ unsigned perm18(unsigned i) {
    unsigned s = i;
    s ^= s >> 1; s ^= s >> 2; s ^= s >> 4; s ^= s >> 8; s ^= s >> 16;
    // s_p = parity(i >> p)
    unsigned out = s & 0x1FFFFu;
    out |= ((s ^ (i >> 17)) & 1u) << 17;   // bit17 = parity(bits 0..16)
    return out;
}

// ---- gate table: cs[l*18+w] = (cos(th/2), sin(th/2)) -----------------------
__global__ void k_setup(const float* qw, float2* cs) {
    int t = threadIdx.x;
    if (t < NL * NW) {
        float th = qw[t] * 0.5f;
        cs[t] = make_float2(cosf(th), sinf(th));
    }
}

// ---- layer 0: product state written with P folded in -----------------------
// amp_j(i) = m * (-i)^k ; m = prod over bits of (c or s); k = #s-factors.
__global__ __launch_bounds__(256) void k_init(const float2* cs, float2* buf0) {
    unsigned i = blockIdx.x * 256u + threadIdx.x;
    float c[NW], s[NW];
#pragma unroll
    for (int w = 0; w < NW; ++w) { float2 v = cs[w]; c[w] = v.x; s[w] = v.y; }
    // address bits p=4..17 (wires 13..0), all start |0>
    float mA = 1.0f;
#pragma unroll
    for (int p = 4; p < 18; ++p) {
        int w = 17 - p;
        mA *= ((i >> p) & 1u) ? s[w] : c[w];
    }
    int kA = __popc(i >> 4);
    unsigned Pi = perm18(i);
    unsigned il = i & 15u;
#pragma unroll
    for (int j = 0; j < 16; ++j) {
        unsigned x = il ^ (unsigned)j;     // mismatch pattern on data bits
        float m = mA;
#pragma unroll
        for (int p = 0; p < 4; ++p) {
            int w = 17 - p;
            m *= ((x >> p) & 1u) ? s[w] : c[w];
        }
        int k = (kA + __popc(x)) & 3;
        float2 a;
        if      (k == 0) a = make_float2( m, 0.f);
        else if (k == 1) a = make_float2(0.f, -m);
        else if (k == 2) a = make_float2(-m, 0.f);
        else             a = make_float2(0.f,  m);
        buf0[(size_t)j * DIM + Pi] = a;
    }
}

// ---- pass A: 13 RX gates on bits 0..12 (wires 5..17), in-place -------------
__global__ __launch_bounds__(256) void k_passA(float2* buf, const float2* cs, int layer) {
    __shared__ float2 t[8192];
    int bx = blockIdx.x;              // 512 = 16 j * 32 blocks
    int j = bx >> 5, blk = bx & 31;
    size_t base = (size_t)j * DIM + (size_t)blk * 8192;
    for (int k = threadIdx.x; k < 8192; k += 256) t[k] = buf[base + k];
    __syncthreads();
    for (int p = 0; p <= 12; ++p) {
        float2 g = cs[layer * NW + (17 - p)];
        float c = g.x, s = g.y;
        int mlow = (1 << p) - 1;
        for (int k = threadIdx.x; k < 4096; k += 256) {
            int i0 = ((k >> p) << (p + 1)) | (k & mlow);
            int i1 = i0 | (1 << p);
            float2 a0 = t[i0], a1 = t[i1];
            t[i0] = make_float2(c * a0.x + s * a1.y, c * a0.y - s * a1.x);
            t[i1] = make_float2(c * a1.x + s * a0.y, c * a1.y - s * a0.x);
        }
        __syncthreads();
    }
    for (int k = threadIdx.x; k < 8192; k += 256) buf[base + k] = t[k];
}

// ---- pass B: 5 RX gates on bits 13..17 (wires 0..4) + P scatter ------------
// If probs != nullptr: emit |amp|^2 instead of the state (final layer).
__global__ __launch_bounds__(256) void k_passB(const float2* in, float2* out,
                                               float* probs, const float2* cs, int layer) {
    __shared__ float2 t[32 * 256];
    int bx = blockIdx.x;              // 512 = 16 j * 32 m
    int j = bx >> 5, m = bx & 31;
    const float2* src = in + (size_t)j * DIM;
    for (int k = threadIdx.x; k < 8192; k += 256) {
        int h = k >> 8, low = k & 255;
        t[k] = src[((size_t)h << 13) | (m << 8) | low];
    }
    __syncthreads();
    for (int q = 0; q <= 4; ++q) {
        float2 g = cs[layer * NW + (4 - q)];   // bit 13+q -> wire 4-q
        float c = g.x, s = g.y;
        int mq = (1 << q) - 1;
        for (int k = threadIdx.x; k < 4096; k += 256) {
            int hh = k >> 8, low = k & 255;
            int h0 = ((hh >> q) << (q + 1)) | (hh & mq);
            int h1 = h0 | (1 << q);
            int i0 = h0 * 256 + low, i1 = h1 * 256 + low;
            float2 a0 = t[i0], a1 = t[i1];
            t[i0] = make_float2(c * a0.x + s * a1.y, c * a0.y - s * a1.x);
            t[i1] = make_float2(c * a1.x + s * a0.y, c * a1.y - s * a0.x);
        }
        __syncthreads();
    }
    if (probs) {
        for (int k = threadIdx.x; k < 8192; k += 256) {
            int h = k >> 8, low = k & 255;
            unsigned i = ((unsigned)h << 13) | (m << 8) | low;
            float2 a = t[k];
            probs[(size_t)j * DIM + perm18(i)] = a.x * a.x + a.y * a.y;
        }
    } else {
        for (int k = threadIdx.x; k < 8192; k += 256) {
            int h = k >> 8, low = k & 255;
            unsigned i = ((unsigned)h << 13) | (m << 8) | low;
            out[(size_t)j * DIM + perm18(i)] = t[k];
        }
    }
}

// ---- probs(16 x DIM) @ W^T(DIM x 64): per-block partials over 4 chunks -----
__global__ __launch_bounds__(256) void k_mm(const float* probs, const float* W, float* partial) {
    __shared__ float Pl[16][MM_CH + 1];
    __shared__ float Wl[64][MM_CH + 1];
    int blk = blockIdx.x;             // 512 blocks, 4 chunks each
    int j = threadIdx.x >> 4, og = threadIdx.x & 15;
    float a0 = 0.f, a1 = 0.f, a2 = 0.f, a3 = 0.f;
    for (int cc = 0; cc < MM_CPB; ++cc) {
        int chunk = blk * MM_CPB + cc;
        size_t d0 = (size_t)chunk * MM_CH;
        __syncthreads();
        for (int k = threadIdx.x; k < 16 * MM_CH; k += 256) {
            int jj = k / MM_CH, d = k % MM_CH;
            Pl[jj][d] = probs[(size_t)jj * DIM + d0 + d];
        }
        for (int k = threadIdx.x; k < 64 * MM_CH; k += 256) {
            int o = k / MM_CH, d = k % MM_CH;
            Wl[o][d] = W[(size_t)o * DIM + d0 + d];
        }
        __syncthreads();
        for (int d = 0; d < MM_CH; ++d) {
            float p = Pl[j][d];
            a0 += p * Wl[og][d];
            a1 += p * Wl[og + 16][d];
            a2 += p * Wl[og + 32][d];
            a3 += p * Wl[og + 48][d];
        }
    }
    float* dst = partial + (size_t)blk * 1024 + j * 64;
    dst[og] = a0; dst[og + 16] = a1; dst[og + 32] = a2; dst[og + 48] = a3;
}

// ---- reduce partials -> logits[16][64] (+bias), coalesced ------------------
// 64 blocks; block b owns jo in [b*16, b*16+16). Threads = 16 chunk-lanes x
// 16 jo-lanes, so each wave's loads are contiguous 64B segments.
__global__ __launch_bounds__(256) void k_reduce(const float* partial, const float* bias, float* logits) {
    int b = blockIdx.x;
    int ji = threadIdx.x & 15, ci = threadIdx.x >> 4;   // ci in 0..15
    int jo = b * 16 + ji;
    float sum = 0.f;
#pragma unroll 8
    for (int c = ci; c < MM_BLOCKS; c += 16)
        sum += partial[(size_t)c * 1024 + jo];
    __shared__ float red[16][17];
    red[ci][ji] = sum;
    __syncthreads();
    if (ci == 0) {
        float s = 0.f;
#pragma unroll
        for (int k = 0; k < 16; ++k) s += red[k][ji];
        logits[jo] = s + bias[jo & 63];
    }
}

// ---- final: per-batch lookup + sigmoid -------------------------------------
__global__ void k_out(const int* x, const float* logits, float* out) {
    int t = blockIdx.x * 256 + threadIdx.x;    // grid 8 -> 2048
    int b = t >> 6, o = t & 63;
    const int* xb = x + (size_t)b * (16384 * 4);
    int idx = 8 * xb[0] + 4 * xb[1] + 2 * xb[2] + xb[3];
    float z = logits[idx * 64 + o];
    out[t] = 1.f / (1.f + expf(-z));
}

extern "C" void kernel_launch(void* const* d_in, const int* in_sizes, int n_in,
                              void* d_out, int out_size, void* d_ws, size_t ws_size,
                              hipStream_t stream) {
    const int*   x    = (const int*)d_in[0];
    const float* qw   = (const float*)d_in[1];
    const float* W    = (const float*)d_in[2];
    const float* bias = (const float*)d_in[3];
    float* out = (float*)d_out;

    char* ws = (char*)d_ws;
    // layout: [0,576) cs | [4K,8K) logits | [1M, 1M+32M) buf0 | [1M+32M, 1M+64M) buf1
    // probs aliases buf1 (16MB), partial aliases buf0 (2MB) -- both safe by ordering.
    float2* cs      = (float2*)ws;
    float*  logits  = (float*)(ws + 4096);
    float2* buf0    = (float2*)(ws + (1 << 20));
    float2* buf1    = (float2*)(ws + (1 << 20) + (size_t)DIM * 16 * sizeof(float2));
    float*  probs   = (float*)buf1;
    float*  partial = (float*)buf0;

    k_setup<<<1, 128, 0, stream>>>(qw, cs);
    k_init<<<DIM / 256, 256, 0, stream>>>(cs, buf0);

    // layers 1..3 (layer 0 done analytically by k_init)
    // l=1: A in-place buf0, B buf0->buf1
    // l=2: A in-place buf1, B buf1->buf0
    // l=3: A in-place buf0, B buf0->probs (|.|^2)
    k_passA<<<512, 256, 0, stream>>>(buf0, cs, 1);
    k_passB<<<512, 256, 0, stream>>>(buf0, buf1, nullptr, cs, 1);
    k_passA<<<512, 256, 0, stream>>>(buf1, cs, 2);
    k_passB<<<512, 256, 0, stream>>>(buf1, buf0, nullptr, cs, 2);
    k_passA<<<512, 256, 0, stream>>>(buf0, cs, 3);
    k_passB<<<512, 256, 0, stream>>>(buf0, nullptr, probs, cs, 3);

    k_mm<<<MM_BLOCKS, 256, 0, stream>>>(probs, W, partial);
    k_reduce<<<64, 256, 0, stream>>>(partial, bias, logits);
    k_out<<<8, 256, 0, stream>>>(x, logits, out);
}

// Round 3
// 127.968 us; speedup vs baseline: 2.5078x; 1.8809x over previous
//
#include <hip/hip_runtime.h>
#include <math.h>

// QNN, exploiting: (1) all gates are GF(2)-convolutions and the CNOT cascade
// is a linear bit-permutation P  =>  the 16 initial basis states evolve into
// XOR-translates of ONE simulated state: probs_j(i) = probs_0(i ^ P^4(j)).
// Simulate a single 2^18 complex state (2 MB), then
// logits[j][o] = sum_d probs_0(d ^ T_j) * W[o][d] + b[o].
//
// Bit convention: wire w <-> bit p = 17-w.  P: out bit q (q<=16) =
// parity(i>>q); out bit 17 = parity(i & 0x1FFFF).

#define DIM (1 << 18)
#define NW 18
#define NL 4
#define CH 128                      // k_mm chunk (d per LDS stage)
#define CPB 4                       // chunks per k_mm block
#define NMM 512                     // k_mm blocks = DIM/(CH*CPB)

__device__ __forceinline__ unsigned perm18(unsigned i) {
    unsigned s = i;
    s ^= s >> 1; s ^= s >> 2; s ^= s >> 4; s ^= s >> 8; s ^= s >> 16;
    unsigned out = s & 0x1FFFFu;
    out |= ((s ^ (i >> 17)) & 1u) << 17;
    return out;
}

__device__ __forceinline__ unsigned pinv18(unsigned b) {
    unsigned t = b & 0x1FFFFu;                 // s_0..s_16
    unsigned u = (t ^ (t >> 1)) & 0xFFFFu;     // i_0..i_15
    unsigned i17 = ((b >> 17) ^ t) & 1u;
    unsigned i16 = ((t >> 16) ^ i17) & 1u;
    return u | (i16 << 16) | (i17 << 17);
}

__device__ __forceinline__ void bfly(float2& a0, float2& a1, float c, float s) {
    float2 n0 = make_float2(c * a0.x + s * a1.y, c * a0.y - s * a1.x);
    float2 n1 = make_float2(c * a1.x + s * a0.y, c * a1.y - s * a0.x);
    a0 = n0; a1 = n1;
}

// ---- gate table cs[l*18+w] = (cos(th/2), sin(th/2)); T[j] = P^4(j) ---------
__global__ void k_setup(const float* qw, float2* cs, unsigned* T) {
    int t = threadIdx.x;
    if (t < NL * NW) {
        float th = qw[t] * 0.5f;
        cs[t] = make_float2(cosf(th), sinf(th));
    }
    if (t < 16) {
        unsigned v = (unsigned)t;
        for (int r = 0; r < 4; ++r) v = perm18(v);
        T[t] = v;
    }
}

// ---- fused: analytic layer-0 output (post-P basis) + layer-1 gates bits0..11
__global__ __launch_bounds__(256) void k_initA(float2* buf, const float2* cs) {
    __shared__ float2 t[4096];
    unsigned base = blockIdx.x * 4096u;
    float c[NW], s[NW];
#pragma unroll
    for (int w = 0; w < NW; ++w) { float2 v = cs[w]; c[w] = v.x; s[w] = v.y; }
    for (int k = threadIdx.x; k < 4096; k += 256) {
        unsigned i = pinv18(base + k);
        float m = 1.0f;
#pragma unroll
        for (int p = 0; p < 18; ++p)
            m *= ((i >> p) & 1u) ? s[17 - p] : c[17 - p];
        int k4 = __popc(i) & 3;
        float2 a;
        if      (k4 == 0) a = make_float2( m, 0.f);
        else if (k4 == 1) a = make_float2(0.f, -m);
        else if (k4 == 2) a = make_float2(-m, 0.f);
        else              a = make_float2(0.f,  m);
        t[k] = a;
    }
    __syncthreads();
    for (int p = 0; p <= 11; ++p) {              // layer 1, wires 17-p
        float2 g = cs[1 * NW + (17 - p)];
        int mlow = (1 << p) - 1;
        for (int k = threadIdx.x; k < 2048; k += 256) {
            int i0 = ((k >> p) << (p + 1)) | (k & mlow);
            int i1 = i0 | (1 << p);
            bfly(t[i0], t[i1], g.x, g.y);
        }
        __syncthreads();
    }
    for (int k = threadIdx.x; k < 4096; k += 256) buf[base + k] = t[k];
}

// ---- pass A: 12 RX gates on bits 0..11, in-place, 64 blocks x 4096 ---------
__global__ __launch_bounds__(256) void k_passA(float2* buf, const float2* cs, int layer) {
    __shared__ float2 t[4096];
    unsigned base = blockIdx.x * 4096u;
    for (int k = threadIdx.x; k < 4096; k += 256) t[k] = buf[base + k];
    __syncthreads();
    for (int p = 0; p <= 11; ++p) {
        float2 g = cs[layer * NW + (17 - p)];
        int mlow = (1 << p) - 1;
        for (int k = threadIdx.x; k < 2048; k += 256) {
            int i0 = ((k >> p) << (p + 1)) | (k & mlow);
            int i1 = i0 | (1 << p);
            bfly(t[i0], t[i1], g.x, g.y);
        }
        __syncthreads();
    }
    for (int k = threadIdx.x; k < 4096; k += 256) buf[base + k] = t[k];
}

// ---- pass B: 6 RX gates on bits 12..17 + perm P scatter --------------------
// tile: 64 hi values (bits 12..17) x 64 contiguous (bits 0..5); block = bits 6..11.
// If probs != nullptr, emit |amp|^2 (final layer).
__global__ __launch_bounds__(256) void k_passB(const float2* in, float2* out,
                                               float* probs, const float2* cs, int layer) {
    __shared__ float2 t[4096];
    int m = blockIdx.x;                          // bits 6..11
    for (int k = threadIdx.x; k < 4096; k += 256) {
        int h = k >> 6, lo = k & 63;
        t[k] = in[((unsigned)h << 12) | (m << 6) | lo];
    }
    __syncthreads();
    for (int q = 0; q <= 5; ++q) {               // bit 12+q -> wire 5-q
        float2 g = cs[layer * NW + (5 - q)];
        int mq = (1 << q) - 1;
        for (int k = threadIdx.x; k < 2048; k += 256) {
            int hh = k >> 6, lo = k & 63;
            int h0 = ((hh >> q) << (q + 1)) | (hh & mq);
            int h1 = h0 | (1 << q);
            bfly(t[(h0 << 6) | lo], t[(h1 << 6) | lo], g.x, g.y);
        }
        __syncthreads();
    }
    if (probs) {
        for (int k = threadIdx.x; k < 4096; k += 256) {
            int h = k >> 6, lo = k & 63;
            unsigned i = ((unsigned)h << 12) | (m << 6) | lo;
            float2 a = t[k];
            probs[perm18(i)] = a.x * a.x + a.y * a.y;
        }
    } else {
        for (int k = threadIdx.x; k < 4096; k += 256) {
            int h = k >> 6, lo = k & 63;
            unsigned i = ((unsigned)h << 12) | (m << 6) | lo;
            out[perm18(i)] = t[k];
        }
    }
}

// ---- logits partials: p0 translated-gather + W stream, 4j x 4o reg tile ----
// thread = (dq:2 | jg:2 | og:4); j = jg*4+u, o = og+16v.
__global__ __launch_bounds__(256) void k_mm(const float* __restrict__ p0,
                                            const float* __restrict__ W,
                                            const unsigned* __restrict__ T,
                                            float* __restrict__ partial) {
    __shared__ float Pl[16][132];
    __shared__ float Wl[64][132];
    __shared__ unsigned Tsh[16];
    int tid = threadIdx.x;
    if (tid < 16) Tsh[tid] = T[tid];
    int dq = tid >> 6, jg = (tid >> 4) & 3, og = tid & 15;
    float acc[4][4] = {};
    for (int cc = 0; cc < CPB; ++cc) {
        unsigned d0 = ((unsigned)blockIdx.x * CPB + cc) * CH;
        __syncthreads();
        for (int k4 = tid; k4 < 64 * CH / 4; k4 += 256) {   // W stage (float4)
            int o = k4 >> 5, dd4 = k4 & 31;
            float4 w = *(const float4*)&W[(size_t)o * DIM + d0 + dd4 * 4];
            *(float4*)&Wl[o][dd4 * 4] = w;
        }
        for (int k = tid; k < 16 * CH; k += 256) {          // p0 translated stage
            int j = k >> 7, mm2 = k & 127;
            unsigned Tj = Tsh[j];
            Pl[j][mm2 ^ (Tj & 127u)] = p0[(d0 ^ (Tj & ~127u)) + mm2];
        }
        __syncthreads();
#pragma unroll 4
        for (int it = 0; it < CH / 8; ++it) {
            int d = dq * 2 + it * 8;
            float2 pa = *(const float2*)&Pl[jg * 4 + 0][d];
            float2 pb = *(const float2*)&Pl[jg * 4 + 1][d];
            float2 pc = *(const float2*)&Pl[jg * 4 + 2][d];
            float2 pd = *(const float2*)&Pl[jg * 4 + 3][d];
            float2 w0 = *(const float2*)&Wl[og][d];
            float2 w1 = *(const float2*)&Wl[og + 16][d];
            float2 w2 = *(const float2*)&Wl[og + 32][d];
            float2 w3 = *(const float2*)&Wl[og + 48][d];
            acc[0][0] += pa.x * w0.x + pa.y * w0.y;
            acc[0][1] += pa.x * w1.x + pa.y * w1.y;
            acc[0][2] += pa.x * w2.x + pa.y * w2.y;
            acc[0][3] += pa.x * w3.x + pa.y * w3.y;
            acc[1][0] += pb.x * w0.x + pb.y * w0.y;
            acc[1][1] += pb.x * w1.x + pb.y * w1.y;
            acc[1][2] += pb.x * w2.x + pb.y * w2.y;
            acc[1][3] += pb.x * w3.x + pb.y * w3.y;
            acc[2][0] += pc.x * w0.x + pc.y * w0.y;
            acc[2][1] += pc.x * w1.x + pc.y * w1.y;
            acc[2][2] += pc.x * w2.x + pc.y * w2.y;
            acc[2][3] += pc.x * w3.x + pc.y * w3.y;
            acc[3][0] += pd.x * w0.x + pd.y * w0.y;
            acc[3][1] += pd.x * w1.x + pd.y * w1.y;
            acc[3][2] += pd.x * w2.x + pd.y * w2.y;
            acc[3][3] += pd.x * w3.x + pd.y * w3.y;
        }
    }
    __syncthreads();
    float* red = &Wl[0][0];                     // reuse: 16*256 floats
#pragma unroll
    for (int u = 0; u < 4; ++u)
#pragma unroll
        for (int v = 0; v < 4; ++v)
            red[(u * 4 + v) * 256 + tid] = acc[u][v];
    __syncthreads();
    if (tid < 64) {
        int jg2 = tid >> 4, og2 = tid & 15;
#pragma unroll
        for (int u = 0; u < 4; ++u)
#pragma unroll
            for (int v = 0; v < 4; ++v) {
                int idx = u * 4 + v;
                float ssum = red[idx * 256 + tid] + red[idx * 256 + 64 + tid]
                           + red[idx * 256 + 128 + tid] + red[idx * 256 + 192 + tid];
                partial[(size_t)blockIdx.x * 1024 + (jg2 * 4 + u) * 64 + og2 + 16 * v] = ssum;
            }
    }
}

// ---- reduce partials -> logits[16][64] (+bias), coalesced ------------------
__global__ __launch_bounds__(256) void k_reduce(const float* partial, const float* bias, float* logits) {
    int b = blockIdx.x;
    int ji = threadIdx.x & 15, ci = threadIdx.x >> 4;
    int jo = b * 16 + ji;
    float sum = 0.f;
#pragma unroll 8
    for (int c = ci; c < NMM; c += 16)
        sum += partial[(size_t)c * 1024 + jo];
    __shared__ float red[16][17];
    red[ci][ji] = sum;
    __syncthreads();
    if (ci == 0) {
        float s = 0.f;
#pragma unroll
        for (int k = 0; k < 16; ++k) s += red[k][ji];
        logits[jo] = s + bias[jo & 63];
    }
}

// ---- final: per-batch lookup + sigmoid -------------------------------------
__global__ void k_out(const int* x, const float* logits, float* out) {
    int t = blockIdx.x * 256 + threadIdx.x;    // 2048
    int b = t >> 6, o = t & 63;
    const int* xb = x + (size_t)b * (16384 * 4);
    int idx = 8 * xb[0] + 4 * xb[1] + 2 * xb[2] + xb[3];
    float z = logits[idx * 64 + o];
    out[t] = 1.f / (1.f + expf(-z));
}

extern "C" void kernel_launch(void* const* d_in, const int* in_sizes, int n_in,
                              void* d_out, int out_size, void* d_ws, size_t ws_size,
                              hipStream_t stream) {
    const int*   x    = (const int*)d_in[0];
    const float* qw   = (const float*)d_in[1];
    const float* W    = (const float*)d_in[2];
    const float* bias = (const float*)d_in[3];
    float* out = (float*)d_out;

    char* ws = (char*)d_ws;
    float2*   cs      = (float2*)ws;                       // 576 B
    unsigned* T       = (unsigned*)(ws + 4096);            // 64 B
    float*    logits  = (float*)(ws + 8192);               // 4 KB
    float2*   buf0    = (float2*)(ws + (1ull << 20));      // 2 MB
    float2*   buf1    = (float2*)(ws + (4ull << 20));      // 2 MB
    float*    probs   = (float*)(ws + (8ull << 20));       // 1 MB
    float*    partial = (float*)(ws + (12ull << 20));      // 2 MB

    k_setup<<<1, 128, 0, stream>>>(qw, cs, T);
    // layer 0 analytic + layer-1 low gates fused:
    k_initA<<<64, 256, 0, stream>>>(buf0, cs);
    k_passB<<<64, 256, 0, stream>>>(buf0, buf1, nullptr, cs, 1);
    k_passA<<<64, 256, 0, stream>>>(buf1, cs, 2);
    k_passB<<<64, 256, 0, stream>>>(buf1, buf0, nullptr, cs, 2);
    k_passA<<<64, 256, 0, stream>>>(buf0, cs, 3);
    k_passB<<<64, 256, 0, stream>>>(buf0, nullptr, probs, cs, 3);

    k_mm<<<NMM, 256, 0, stream>>>(probs, W, T, partial);
    k_reduce<<<64, 256, 0, stream>>>(partial, bias, logits);
    k_out<<<8, 256, 0, stream>>>(x, logits, out);
}

// Round 4
// 124.344 us; speedup vs baseline: 2.5809x; 1.0291x over previous
//
#include <hip/hip_runtime.h>
#include <math.h>

// QNN: all gates are GF(2)-convolutions and the CNOT cascade is a linear bit
// permutation P  =>  the 16 initial basis states evolve into XOR-translates
// of ONE simulated state: probs_j(i) = probs_0(i ^ P^4(j)).
// Simulate a single 2^18 complex state (2 MB), then
// logits[j][o] = sum_d probs_0(d ^ T_j) * W[o][d] + b[o].
//
// Bit convention: wire w <-> bit p = 17-w.  P: out bit q (q<=16) =
// parity(i>>q); out bit 17 = parity(i & 0x1FFFF).

#define DIM (1 << 18)
#define NW 18
#define CH 64                       // k_mm chunk (d per LDS stage)
#define CPB 8                       // chunks per k_mm block
#define NMM 512                     // k_mm blocks = DIM/(CH*CPB)

__device__ __forceinline__ unsigned perm18(unsigned i) {
    unsigned s = i;
    s ^= s >> 1; s ^= s >> 2; s ^= s >> 4; s ^= s >> 8; s ^= s >> 16;
    unsigned out = s & 0x1FFFFu;
    out |= ((s ^ (i >> 17)) & 1u) << 17;
    return out;
}

__device__ __forceinline__ unsigned pinv18(unsigned b) {
    unsigned t = b & 0x1FFFFu;                 // s_0..s_16
    unsigned u = (t ^ (t >> 1)) & 0xFFFFu;     // i_0..i_15
    unsigned i17 = ((b >> 17) ^ t) & 1u;
    unsigned i16 = ((t >> 16) ^ i17) & 1u;
    return u | (i16 << 16) | (i17 << 17);
}

__device__ __forceinline__ void bfly(float2& a0, float2& a1, float c, float s) {
    float2 n0 = make_float2(c * a0.x + s * a1.y, c * a0.y - s * a1.x);
    float2 n1 = make_float2(c * a1.x + s * a0.y, c * a1.y - s * a0.x);
    a0 = n0; a1 = n1;
}

// ---- fused: analytic layer-0 output (post-P basis) + layer-1 gates bits0..11
__global__ __launch_bounds__(256) void k_initA(float2* buf, const float* qw) {
    __shared__ float2 t[4096];
    __shared__ float2 g1[12];
    int tid = threadIdx.x;
    if (tid < 12) {                            // layer-1 gate for bit p=tid
        float th = qw[1 * NW + (17 - tid)] * 0.5f;
        g1[tid] = make_float2(cosf(th), sinf(th));
    }
    float c[NW], s[NW];
#pragma unroll
    for (int w = 0; w < NW; ++w) {
        float th = qw[w] * 0.5f;
        c[w] = cosf(th); s[w] = sinf(th);
    }
    unsigned base = blockIdx.x * 4096u;
    for (int k = tid; k < 4096; k += 256) {
        unsigned i = pinv18(base + k);
        float m = 1.0f;
#pragma unroll
        for (int p = 0; p < 18; ++p)
            m *= ((i >> p) & 1u) ? s[17 - p] : c[17 - p];
        int k4 = __popc(i) & 3;
        float2 a;
        if      (k4 == 0) a = make_float2( m, 0.f);
        else if (k4 == 1) a = make_float2(0.f, -m);
        else if (k4 == 2) a = make_float2(-m, 0.f);
        else              a = make_float2(0.f,  m);
        t[k] = a;
    }
    __syncthreads();
    for (int p = 0; p <= 11; ++p) {
        float2 g = g1[p];
        int mlow = (1 << p) - 1;
        for (int k = tid; k < 2048; k += 256) {
            int i0 = ((k >> p) << (p + 1)) | (k & mlow);
            int i1 = i0 | (1 << p);
            bfly(t[i0], t[i1], g.x, g.y);
        }
        __syncthreads();
    }
    for (int k = tid; k < 4096; k += 256) buf[base + k] = t[k];
}

// ---- pass A: 12 RX gates on bits 0..11, in-place, 64 blocks x 4096 ---------
__global__ __launch_bounds__(256) void k_passA(float2* buf, const float* qw, int layer) {
    __shared__ float2 t[4096];
    __shared__ float2 g[12];
    int tid = threadIdx.x;
    if (tid < 12) {
        float th = qw[layer * NW + (17 - tid)] * 0.5f;
        g[tid] = make_float2(cosf(th), sinf(th));
    }
    unsigned base = blockIdx.x * 4096u;
    for (int k = tid; k < 4096; k += 256) t[k] = buf[base + k];
    __syncthreads();
    for (int p = 0; p <= 11; ++p) {
        float2 gg = g[p];
        int mlow = (1 << p) - 1;
        for (int k = tid; k < 2048; k += 256) {
            int i0 = ((k >> p) << (p + 1)) | (k & mlow);
            int i1 = i0 | (1 << p);
            bfly(t[i0], t[i1], gg.x, gg.y);
        }
        __syncthreads();
    }
    for (int k = tid; k < 4096; k += 256) buf[base + k] = t[k];
}

// ---- pass B: 6 RX gates on bits 12..17 + perm P scatter --------------------
// tile: 64 hi (bits 12..17) x 64 contiguous (bits 0..5); block = bits 6..11.
// If probs != nullptr, emit |amp|^2 (final layer).
__global__ __launch_bounds__(256) void k_passB(const float2* in, float2* out,
                                               float* probs, const float* qw, int layer) {
    __shared__ float2 t[4096];
    __shared__ float2 g[6];
    int tid = threadIdx.x;
    if (tid < 6) {                              // bit 12+q -> wire 5-q
        float th = qw[layer * NW + (5 - tid)] * 0.5f;
        g[tid] = make_float2(cosf(th), sinf(th));
    }
    int m = blockIdx.x;                         // bits 6..11
    for (int k = tid; k < 4096; k += 256) {
        int h = k >> 6, lo = k & 63;
        t[k] = in[((unsigned)h << 12) | (m << 6) | lo];
    }
    __syncthreads();
    for (int q = 0; q <= 5; ++q) {
        float2 gg = g[q];
        int mq = (1 << q) - 1;
        for (int k = tid; k < 2048; k += 256) {
            int hh = k >> 6, lo = k & 63;
            int h0 = ((hh >> q) << (q + 1)) | (hh & mq);
            int h1 = h0 | (1 << q);
            bfly(t[(h0 << 6) | lo], t[(h1 << 6) | lo], gg.x, gg.y);
        }
        __syncthreads();
    }
    if (probs) {
        for (int k = tid; k < 4096; k += 256) {
            int h = k >> 6, lo = k & 63;
            unsigned i = ((unsigned)h << 12) | (m << 6) | lo;
            float2 a = t[k];
            probs[perm18(i)] = a.x * a.x + a.y * a.y;
        }
    } else {
        for (int k = tid; k < 4096; k += 256) {
            int h = k >> 6, lo = k & 63;
            unsigned i = ((unsigned)h << 12) | (m << 6) | lo;
            out[perm18(i)] = t[k];
        }
    }
}

// ---- logits partials: T14 async-stage + double-buffered LDS ----------------
// thread = (dq:2 | jg:2 | og:4); accumulates 4j x 4o.
__global__ __launch_bounds__(256) void k_mm(const float* __restrict__ p0,
                                            const float* __restrict__ W,
                                            float* __restrict__ partial) {
    __shared__ float Wl[2][64][68];
    __shared__ float Pl[2][16][68];
    __shared__ unsigned Tsh[16];
    int tid = threadIdx.x;
    if (tid < 16) {
        unsigned v = (unsigned)tid;
        for (int r = 0; r < 4; ++r) v = perm18(v);
        Tsh[tid] = v;
    }
    __syncthreads();
    // staging geometry
    int so = tid >> 4;                 // W row within group of 16
    int sd = (tid & 15) * 4;           // float4 col
    int sj = tid >> 6;                 // base j row per i
    int sm = tid & 63;
    unsigned Tj[4];
#pragma unroll
    for (int i = 0; i < 4; ++i) Tj[i] = Tsh[i * 4 + sj];
    int dq = tid >> 6, jg = (tid >> 4) & 3, og = tid & 15;
    unsigned d00 = (unsigned)blockIdx.x * (CH * CPB);

    float4 wreg[4];
    float  preg[4];
    float acc[4][4] = {};

    // prologue: stage chunk 0 into buffer 0
    {
        unsigned d0 = d00;
#pragma unroll
        for (int i = 0; i < 4; ++i)
            wreg[i] = *(const float4*)&W[(size_t)(i * 16 + so) * DIM + d0 + sd];
#pragma unroll
        for (int i = 0; i < 4; ++i)
            preg[i] = p0[(d0 ^ (Tj[i] & ~63u)) + sm];
#pragma unroll
        for (int i = 0; i < 4; ++i)
            *(float4*)&Wl[0][i * 16 + so][sd] = wreg[i];
#pragma unroll
        for (int i = 0; i < 4; ++i)
            Pl[0][i * 4 + sj][sm ^ (Tj[i] & 63u)] = preg[i];
    }
    __syncthreads();

    for (int cc = 0; cc < CPB; ++cc) {
        // issue next chunk's global loads (latency hides under compute below)
        if (cc + 1 < CPB) {
            unsigned d0 = d00 + (unsigned)(cc + 1) * CH;
#pragma unroll
            for (int i = 0; i < 4; ++i)
                wreg[i] = *(const float4*)&W[(size_t)(i * 16 + so) * DIM + d0 + sd];
#pragma unroll
            for (int i = 0; i < 4; ++i)
                preg[i] = p0[(d0 ^ (Tj[i] & ~63u)) + sm];
        }
        int b = cc & 1;
#pragma unroll
        for (int it = 0; it < CH / 8; ++it) {
            int d = dq * 2 + it * 8;
            float2 pa = *(const float2*)&Pl[b][jg * 4 + 0][d];
            float2 pb = *(const float2*)&Pl[b][jg * 4 + 1][d];
            float2 pc = *(const float2*)&Pl[b][jg * 4 + 2][d];
            float2 pd = *(const float2*)&Pl[b][jg * 4 + 3][d];
            float2 w0 = *(const float2*)&Wl[b][og][d];
            float2 w1 = *(const float2*)&Wl[b][og + 16][d];
            float2 w2 = *(const float2*)&Wl[b][og + 32][d];
            float2 w3 = *(const float2*)&Wl[b][og + 48][d];
            acc[0][0] += pa.x * w0.x + pa.y * w0.y;
            acc[0][1] += pa.x * w1.x + pa.y * w1.y;
            acc[0][2] += pa.x * w2.x + pa.y * w2.y;
            acc[0][3] += pa.x * w3.x + pa.y * w3.y;
            acc[1][0] += pb.x * w0.x + pb.y * w0.y;
            acc[1][1] += pb.x * w1.x + pb.y * w1.y;
            acc[1][2] += pb.x * w2.x + pb.y * w2.y;
            acc[1][3] += pb.x * w3.x + pb.y * w3.y;
            acc[2][0] += pc.x * w0.x + pc.y * w0.y;
            acc[2][1] += pc.x * w1.x + pc.y * w1.y;
            acc[2][2] += pc.x * w2.x + pc.y * w2.y;
            acc[2][3] += pc.x * w3.x + pc.y * w3.y;
            acc[3][0] += pd.x * w0.x + pd.y * w0.y;
            acc[3][1] += pd.x * w1.x + pd.y * w1.y;
            acc[3][2] += pd.x * w2.x + pd.y * w2.y;
            acc[3][3] += pd.x * w3.x + pd.y * w3.y;
        }
        if (cc + 1 < CPB) {       // commit staged regs into the other buffer
            int nb = (cc + 1) & 1;
#pragma unroll
            for (int i = 0; i < 4; ++i)
                *(float4*)&Wl[nb][i * 16 + so][sd] = wreg[i];
#pragma unroll
            for (int i = 0; i < 4; ++i)
                Pl[nb][i * 4 + sj][sm ^ (Tj[i] & 63u)] = preg[i];
        }
        __syncthreads();
    }

    // in-block reduction over the 4 dq groups (reuse Wl as scratch)
    float* red = &Wl[0][0][0];            // 16*256 floats = 16 KB
#pragma unroll
    for (int u = 0; u < 4; ++u)
#pragma unroll
        for (int v = 0; v < 4; ++v)
            red[(u * 4 + v) * 256 + tid] = acc[u][v];
    __syncthreads();
    if (tid < 64) {
        int jg2 = tid >> 4, og2 = tid & 15;
#pragma unroll
        for (int u = 0; u < 4; ++u)
#pragma unroll
            for (int v = 0; v < 4; ++v) {
                int idx = u * 4 + v;
                float ssum = red[idx * 256 + tid] + red[idx * 256 + 64 + tid]
                           + red[idx * 256 + 128 + tid] + red[idx * 256 + 192 + tid];
                partial[(size_t)blockIdx.x * 1024 + (jg2 * 4 + u) * 64 + og2 + 16 * v] = ssum;
            }
    }
}

// ---- reduce partials -> logits[16][64] (+bias), coalesced ------------------
__global__ __launch_bounds__(256) void k_reduce(const float* partial, const float* bias, float* logits) {
    int b = blockIdx.x;
    int ji = threadIdx.x & 15, ci = threadIdx.x >> 4;
    int jo = b * 16 + ji;
    float sum = 0.f;
#pragma unroll 8
    for (int c = ci; c < NMM; c += 16)
        sum += partial[(size_t)c * 1024 + jo];
    __shared__ float red[16][17];
    red[ci][ji] = sum;
    __syncthreads();
    if (ci == 0) {
        float s = 0.f;
#pragma unroll
        for (int k = 0; k < 16; ++k) s += red[k][ji];
        logits[jo] = s + bias[jo & 63];
    }
}

// ---- final: per-batch lookup + sigmoid -------------------------------------
__global__ void k_out(const int* x, const float* logits, float* out) {
    int t = blockIdx.x * 256 + threadIdx.x;    // 2048
    int b = t >> 6, o = t & 63;
    const int* xb = x + (size_t)b * (16384 * 4);
    int idx = 8 * xb[0] + 4 * xb[1] + 2 * xb[2] + xb[3];
    float z = logits[idx * 64 + o];
    out[t] = 1.f / (1.f + expf(-z));
}

extern "C" void kernel_launch(void* const* d_in, const int* in_sizes, int n_in,
                              void* d_out, int out_size, void* d_ws, size_t ws_size,
                              hipStream_t stream) {
    const int*   x    = (const int*)d_in[0];
    const float* qw   = (const float*)d_in[1];
    const float* W    = (const float*)d_in[2];
    const float* bias = (const float*)d_in[3];
    float* out = (float*)d_out;

    char* ws = (char*)d_ws;
    float*    logits  = (float*)(ws + 8192);               // 4 KB
    float2*   buf0    = (float2*)(ws + (1ull << 20));      // 2 MB
    float2*   buf1    = (float2*)(ws + (4ull << 20));      // 2 MB
    float*    probs   = (float*)(ws + (8ull << 20));       // 1 MB
    float*    partial = (float*)(ws + (12ull << 20));      // 2 MB

    // layer 0 analytic + layer-1 low gates fused:
    k_initA<<<64, 256, 0, stream>>>(buf0, qw);
    k_passB<<<64, 256, 0, stream>>>(buf0, buf1, nullptr, qw, 1);
    k_passA<<<64, 256, 0, stream>>>(buf1, qw, 2);
    k_passB<<<64, 256, 0, stream>>>(buf1, buf0, nullptr, qw, 2);
    k_passA<<<64, 256, 0, stream>>>(buf0, qw, 3);
    k_passB<<<64, 256, 0, stream>>>(buf0, nullptr, probs, qw, 3);

    k_mm<<<NMM, 256, 0, stream>>>(probs, W, partial);
    k_reduce<<<64, 256, 0, stream>>>(partial, bias, logits);
    k_out<<<8, 256, 0, stream>>>(x, logits, out);
}